// Round 2
// baseline (22.160 us; speedup 1.0000x reference)
//
#include <hip/hip_runtime.h>
#include <math.h>

// BrownianKernelLayer: K[i,j] = 0.5 * sum_d (|x_id|^p + |X2_jd|^p - |x_id - X2_jd|^p)
// p = 2 * softplus(log_H).  N=M=2048, D=16, fp32 in/out.
//
// Structure: 64x64 output tile per block, 256 threads, 4x4 micro-tile/thread.
// x/X2 tiles staged TRANSPOSED in LDS (tile[d][row]) so the 4 row-values a
// thread needs at fixed d are one ds_read_b128 (16B aligned, conflict-free).
//
// |t|^p computed as exp2(p*log2(t)) via v_log_f32/v_exp_f32 hardware ops:
// __builtin_amdgcn_logf -> v_log_f32 (log2), __builtin_amdgcn_exp2f -> v_exp_f32.
// log2(0) = -inf -> exp2(-inf) = 0, so t==0 is handled correctly.

#define D_DIM 16
#define BLK 64

__device__ __forceinline__ float powp(float t, float p) {
    return __builtin_amdgcn_exp2f(p * __builtin_amdgcn_logf(t));
}

__global__ __launch_bounds__(256) void fbm_kernel(
    const float* __restrict__ x,    // [N, 16]
    const float* __restrict__ X2,   // [M, 16]
    const float* __restrict__ logH, // [1]
    float* __restrict__ out,        // [N, M]
    int N, int M)
{
    __shared__ float xs[D_DIM][BLK];   // transposed x tile
    __shared__ float ys[D_DIM][BLK];   // transposed X2 tile
    __shared__ float t1s[BLK];
    __shared__ float t2s[BLK];

    const int tid  = threadIdx.x;
    const int brow = blockIdx.y * BLK;
    const int bcol = blockIdx.x * BLK;

    const float p = 2.0f * log1pf(expf(logH[0]));  // softplus, once per thread

    // ---- stage: 64 rows x 16 d = 1024 floats per tile = 256 threads x float4
    {
        float4 vx = ((const float4*)(x  + (size_t)brow * D_DIM))[tid];
        float4 vy = ((const float4*)(X2 + (size_t)bcol * D_DIM))[tid];
        int r  = tid >> 2;          // row within tile
        int d0 = (tid & 3) << 2;    // starting d
        xs[d0 + 0][r] = vx.x; xs[d0 + 1][r] = vx.y;
        xs[d0 + 2][r] = vx.z; xs[d0 + 3][r] = vx.w;
        ys[d0 + 0][r] = vy.x; ys[d0 + 1][r] = vy.y;
        ys[d0 + 2][r] = vy.z; ys[d0 + 3][r] = vy.w;
    }
    __syncthreads();

    // ---- per-row self terms t1 (x rows) / t2 (X2 rows)
    if (tid < 128) {
        int r = tid & 63;
        const float (*src)[BLK] = (tid < 64) ? xs : ys;
        float s = 0.0f;
        #pragma unroll
        for (int d = 0; d < D_DIM; ++d) {
            s += powp(fabsf(src[d][r]), p);
        }
        if (tid < 64) t1s[r] = s; else t2s[r] = s;
    }
    __syncthreads();

    // ---- main: 4x4 outputs per thread; 16x16 thread grid covers 64x64
    const int ti = tid >> 4;   // 0..15 -> output row group
    const int tj = tid & 15;   // 0..15 -> output col group

    float acc[4][4] = {};

    #pragma unroll
    for (int d = 0; d < D_DIM; ++d) {
        float4 xa = *(const float4*)&xs[d][ti * 4];
        float4 xb = *(const float4*)&ys[d][tj * 4];
        float a0 = xa.x, a1 = xa.y, a2 = xa.z, a3 = xa.w;
        float b0 = xb.x, b1 = xb.y, b2 = xb.z, b3 = xb.w;

        acc[0][0] += powp(fabsf(a0 - b0), p);
        acc[0][1] += powp(fabsf(a0 - b1), p);
        acc[0][2] += powp(fabsf(a0 - b2), p);
        acc[0][3] += powp(fabsf(a0 - b3), p);
        acc[1][0] += powp(fabsf(a1 - b0), p);
        acc[1][1] += powp(fabsf(a1 - b1), p);
        acc[1][2] += powp(fabsf(a1 - b2), p);
        acc[1][3] += powp(fabsf(a1 - b3), p);
        acc[2][0] += powp(fabsf(a2 - b0), p);
        acc[2][1] += powp(fabsf(a2 - b1), p);
        acc[2][2] += powp(fabsf(a2 - b2), p);
        acc[2][3] += powp(fabsf(a2 - b3), p);
        acc[3][0] += powp(fabsf(a3 - b0), p);
        acc[3][1] += powp(fabsf(a3 - b1), p);
        acc[3][2] += powp(fabsf(a3 - b2), p);
        acc[3][3] += powp(fabsf(a3 - b3), p);
    }

    // ---- epilogue: K = 0.5*(t1[i] + t2[j] - t3)
    float t2v0 = t2s[tj * 4 + 0];
    float t2v1 = t2s[tj * 4 + 1];
    float t2v2 = t2s[tj * 4 + 2];
    float t2v3 = t2s[tj * 4 + 3];

    #pragma unroll
    for (int a = 0; a < 4; ++a) {
        float t1v = t1s[ti * 4 + a];
        float4 o;
        o.x = 0.5f * (t1v + t2v0 - acc[a][0]);
        o.y = 0.5f * (t1v + t2v1 - acc[a][1]);
        o.z = 0.5f * (t1v + t2v2 - acc[a][2]);
        o.w = 0.5f * (t1v + t2v3 - acc[a][3]);
        int gi = brow + ti * 4 + a;
        *(float4*)(out + (size_t)gi * M + bcol + tj * 4) = o;
    }
}

extern "C" void kernel_launch(void* const* d_in, const int* in_sizes, int n_in,
                              void* d_out, int out_size, void* d_ws, size_t ws_size,
                              hipStream_t stream) {
    const float* x    = (const float*)d_in[0];
    const float* X2   = (const float*)d_in[1];
    const float* logH = (const float*)d_in[2];
    float* out = (float*)d_out;

    int N = in_sizes[0] / D_DIM;
    int M = in_sizes[1] / D_DIM;

    dim3 grid(M / BLK, N / BLK);
    dim3 block(256);
    fbm_kernel<<<grid, block, 0, stream>>>(x, X2, logH, out, N, M);
}